// Round 9
// baseline (591.428 us; speedup 1.0000x reference)
//
#include <hip/hip_runtime.h>
#include <cstdint>
#include <cstddef>

#define LA 4096
#define LB 4096
#define DD 1024

typedef unsigned short u16;
typedef short bf16x8 __attribute__((ext_vector_type(8)));
typedef float f32x4 __attribute__((ext_vector_type(4)));

__device__ __forceinline__ u16 f2bf(float f) {
  unsigned u = __builtin_bit_cast(unsigned, f);
  u += 0x7fffu + ((u >> 16) & 1u);
  return (u16)(u >> 16);
}
__device__ __forceinline__ float bf2f(u16 h) {
  return __builtin_bit_cast(float, (unsigned)h << 16);
}
__device__ __forceinline__ bf16x8 pack8(float4 a, float4 b) {
  bf16x8 r;
  r[0] = (short)f2bf(a.x); r[1] = (short)f2bf(a.y);
  r[2] = (short)f2bf(a.z); r[3] = (short)f2bf(a.w);
  r[4] = (short)f2bf(b.x); r[5] = (short)f2bf(b.y);
  r[6] = (short)f2bf(b.z); r[7] = (short)f2bf(b.w);
  return r;
}
// split fp32 -> hi + lo bf16 pair
__device__ __forceinline__ void split8(float4 a, float4 b, bf16x8& hi, bf16x8& lo) {
  float v[8] = {a.x, a.y, a.z, a.w, b.x, b.y, b.z, b.w};
#pragma unroll
  for (int i = 0; i < 8; ++i) {
    const u16 h = f2bf(v[i]);
    hi[i] = (short)h;
    lo[i] = (short)f2bf(v[i] - bf2f(h));
  }
}

// ------- tiled transpose fp32 -> bf16: out[c][r] = bf16(in[r][c]) -----------
__global__ __launch_bounds__(256) void tr_f32(const float* __restrict__ in,
                                              u16* __restrict__ out,
                                              int R, int C) {
  __shared__ u16 t[32][33];
  const int c0 = blockIdx.x * 32, r0 = blockIdx.y * 32;
  const int tid = threadIdx.x;
  const int lr = tid >> 3, lc = (tid & 7) * 4;
  const float4 v = *(const float4*)&in[(size_t)(r0 + lr) * C + c0 + lc];
  t[lr][lc + 0] = f2bf(v.x); t[lr][lc + 1] = f2bf(v.y);
  t[lr][lc + 2] = f2bf(v.z); t[lr][lc + 3] = f2bf(v.w);
  __syncthreads();
  ushort4 w;
  w.x = t[lc + 0][lr]; w.y = t[lc + 1][lr]; w.z = t[lc + 2][lr]; w.w = t[lc + 3][lr];
  *(ushort4*)&out[(size_t)(c0 + lr) * R + r0 + lc] = w;
}

// ------- energy = A @ B^T, SPLIT-BF16 (fp32-accurate): 3 MFMA terms ---------
__global__ __launch_bounds__(256) void gemm_energy(const float* __restrict__ A,
                                                   const float* __restrict__ B,
                                                   float* __restrict__ E) {
  __shared__ u16 ah[128 * 40], al[128 * 40], bh[128 * 40], bl[128 * 40];
  const int j0 = blockIdx.x * 128;
  const int i0 = blockIdx.y * 128;
  const int tid = threadIdx.x;
  const int lane = tid & 63, quad = lane >> 4, lq = lane & 15;
  const int wave = tid >> 6;
  const int wm = (wave & 1) * 64, wn = (wave >> 1) * 64;
  f32x4 acc[4][4] = {};
  for (int kt = 0; kt < DD; kt += 32) {
    if (kt) __syncthreads();
#pragma unroll
    for (int r = 0; r < 2; ++r) {
      const int chunk = r * 256 + tid;
      const int row = chunk >> 2;
      const int kc = (chunk & 3) * 8;
      const size_t ba = (size_t)(i0 + row) * DD + kt + kc;
      const size_t bb = (size_t)(j0 + row) * DD + kt + kc;
      bf16x8 hi, lo;
      split8(*(const float4*)&A[ba], *(const float4*)&A[ba + 4], hi, lo);
      *(bf16x8*)&ah[row * 40 + kc] = hi;
      *(bf16x8*)&al[row * 40 + kc] = lo;
      split8(*(const float4*)&B[bb], *(const float4*)&B[bb + 4], hi, lo);
      *(bf16x8*)&bh[row * 40 + kc] = hi;
      *(bf16x8*)&bl[row * 40 + kc] = lo;
    }
    __syncthreads();
    bf16x8 fah[4], fal[4], fbh[4], fbl[4];
#pragma unroll
    for (int f = 0; f < 4; ++f) {
      fah[f] = *(const bf16x8*)&ah[(wm + f * 16 + lq) * 40 + quad * 8];
      fal[f] = *(const bf16x8*)&al[(wm + f * 16 + lq) * 40 + quad * 8];
      fbh[f] = *(const bf16x8*)&bh[(wn + f * 16 + lq) * 40 + quad * 8];
      fbl[f] = *(const bf16x8*)&bl[(wn + f * 16 + lq) * 40 + quad * 8];
    }
#pragma unroll
    for (int fm = 0; fm < 4; ++fm)
#pragma unroll
      for (int fn = 0; fn < 4; ++fn) {
        acc[fm][fn] = __builtin_amdgcn_mfma_f32_16x16x32_bf16(fal[fm], fbh[fn], acc[fm][fn], 0, 0, 0);
        acc[fm][fn] = __builtin_amdgcn_mfma_f32_16x16x32_bf16(fah[fm], fbl[fn], acc[fm][fn], 0, 0, 0);
        acc[fm][fn] = __builtin_amdgcn_mfma_f32_16x16x32_bf16(fah[fm], fbh[fn], acc[fm][fn], 0, 0, 0);
      }
  }
#pragma unroll
  for (int fm = 0; fm < 4; ++fm)
#pragma unroll
    for (int fn = 0; fn < 4; ++fn)
#pragma unroll
      for (int r = 0; r < 4; ++r) {
        const int gi = i0 + wm + fm * 16 + quad * 4 + r;
        const int gj = j0 + wn + fn * 16 + lq;
        E[(size_t)gi * LB + gj] = acc[fm][fn][r];
      }
}

// ---------------- row softmax stats -----------------------------------------
__global__ __launch_bounds__(256) void row_stats(const float* __restrict__ E,
                                                 float* __restrict__ rmax,
                                                 float* __restrict__ rinv) {
  __shared__ float red[8];
  const int row = blockIdx.x, tid = threadIdx.x;
  const float* e = E + (size_t)row * LB;
  float4 v[4];
#pragma unroll
  for (int c = 0; c < 4; ++c) v[c] = *(const float4*)&e[(c * 256 + tid) * 4];
  float m = -__builtin_inff();
#pragma unroll
  for (int c = 0; c < 4; ++c)
    m = fmaxf(m, fmaxf(fmaxf(v[c].x, v[c].y), fmaxf(v[c].z, v[c].w)));
#pragma unroll
  for (int o = 32; o > 0; o >>= 1) m = fmaxf(m, __shfl_down(m, o));
  if ((tid & 63) == 0) red[tid >> 6] = m;
  __syncthreads();
  m = fmaxf(fmaxf(red[0], red[1]), fmaxf(red[2], red[3]));
  float s = 0.f;
#pragma unroll
  for (int c = 0; c < 4; ++c)
    s += __expf(v[c].x - m) + __expf(v[c].y - m) + __expf(v[c].z - m) + __expf(v[c].w - m);
#pragma unroll
  for (int o = 32; o > 0; o >>= 1) s += __shfl_down(s, o);
  if ((tid & 63) == 0) red[4 + (tid >> 6)] = s;
  __syncthreads();
  if (tid == 0) {
    rmax[row] = m;
    rinv[row] = 1.f / (red[4] + red[5] + red[6] + red[7]);
  }
}

// ---------------- column softmax stats --------------------------------------
__global__ __launch_bounds__(256) void col_partial(const float* __restrict__ E,
                                                   float* __restrict__ pmax,
                                                   float* __restrict__ psum) {
  const int c = blockIdx.x * 256 + threadIdx.x;
  const int rg = blockIdx.y;
  const float* e = E + (size_t)rg * 128 * LB + c;
  float m = -__builtin_inff(), s = 0.f;
#pragma unroll 4
  for (int r = 0; r < 128; ++r) {
    const float x = e[(size_t)r * LB];
    const float nm = fmaxf(m, x);
    s = s * __expf(m - nm) + __expf(x - nm);
    m = nm;
  }
  pmax[rg * LB + c] = m;
  psum[rg * LB + c] = s;
}

__global__ __launch_bounds__(256) void col_combine(const float* __restrict__ pmax,
                                                   const float* __restrict__ psum,
                                                   float* __restrict__ cmax,
                                                   float* __restrict__ cinv) {
  const int c = blockIdx.x * 256 + threadIdx.x;
  float m = -__builtin_inff(), s = 0.f;
#pragma unroll 4
  for (int g = 0; g < 32; ++g) {
    const float pm = pmax[g * LB + c], ps = psum[g * LB + c];
    const float nm = fmaxf(m, pm);
    s = s * __expf(m - nm) + ps * __expf(pm - nm);
    m = nm;
  }
  cmax[c] = m;
  cinv[c] = 1.f / s;
}

// ---- Pa[i][j] = bf16(exp(E[i][j] - rmax[i])), full [4096][4096] ------------
__global__ __launch_bounds__(256) void make_pa(const float* __restrict__ E,
                                               const float* __restrict__ rmax,
                                               u16* __restrict__ P) {
  const int i = blockIdx.x;
  const int c = threadIdx.x * 16;
  const float* e = E + (size_t)i * LB + c;
  const float rm = rmax[i];
  const float4 x0 = *(const float4*)(e);
  const float4 x1 = *(const float4*)(e + 4);
  const float4 x2 = *(const float4*)(e + 8);
  const float4 x3 = *(const float4*)(e + 12);
  float4 y0, y1, y2, y3;
  y0.x = __expf(x0.x - rm); y0.y = __expf(x0.y - rm); y0.z = __expf(x0.z - rm); y0.w = __expf(x0.w - rm);
  y1.x = __expf(x1.x - rm); y1.y = __expf(x1.y - rm); y1.z = __expf(x1.z - rm); y1.w = __expf(x1.w - rm);
  y2.x = __expf(x2.x - rm); y2.y = __expf(x2.y - rm); y2.z = __expf(x2.z - rm); y2.w = __expf(x2.w - rm);
  y3.x = __expf(x3.x - rm); y3.y = __expf(x3.y - rm); y3.z = __expf(x3.z - rm); y3.w = __expf(x3.w - rm);
  *(bf16x8*)&P[(size_t)i * LB + c] = pack8(y0, y1);
  *(bf16x8*)&P[(size_t)i * LB + c + 8] = pack8(y2, y3);
}

// ---- Pb[j][i] = bf16(exp(E[i][j] - cmax[j])), transposing, full ------------
__global__ __launch_bounds__(256) void make_pb(const float* __restrict__ E,
                                               const float* __restrict__ cmax,
                                               u16* __restrict__ P) {
  __shared__ u16 t[32][33];
  const int j0 = blockIdx.x * 32;
  const int i0 = blockIdx.y * 32;
  const int tid = threadIdx.x;
  const int lr = tid >> 3, lc = (tid & 7) * 4;
  const float4 v = *(const float4*)&E[(size_t)(i0 + lr) * LB + j0 + lc];
  const float4 cm = *(const float4*)&cmax[j0 + lc];
  t[lr][lc + 0] = f2bf(__expf(v.x - cm.x));
  t[lr][lc + 1] = f2bf(__expf(v.y - cm.y));
  t[lr][lc + 2] = f2bf(__expf(v.z - cm.z));
  t[lr][lc + 3] = f2bf(__expf(v.w - cm.w));
  __syncthreads();
  ushort4 w;
  w.x = t[lc + 0][lr]; w.y = t[lc + 1][lr]; w.z = t[lc + 2][lr]; w.w = t[lc + 3][lr];
  *(ushort4*)&P[(size_t)(j0 + lr) * LA + i0 + lc] = w;
}

// ---- W[i][d] = inv[i] * sum_j P[i][j] Vt[d][j]  -> FP32 output -------------
__global__ __launch_bounds__(256) void gemm_pv(const u16* __restrict__ P,
                                               const u16* __restrict__ Vt,
                                               const float* __restrict__ inv,
                                               float* __restrict__ W) {
  __shared__ u16 lds_a[128 * 40];
  __shared__ u16 lds_b[128 * 40];
  const int n0 = blockIdx.x * 128;
  const int i0 = blockIdx.y * 128;
  const int tid = threadIdx.x;
  const int lane = tid & 63, quad = lane >> 4, lq = lane & 15;
  const int wave = tid >> 6;
  const int wm = (wave & 1) * 64, wn = (wave >> 1) * 64;
  f32x4 acc[4][4] = {};
  for (int kt = 0; kt < 4096; kt += 32) {
    if (kt) __syncthreads();
#pragma unroll
    for (int r = 0; r < 2; ++r) {
      const int chunk = r * 256 + tid;
      const int row = chunk >> 2;
      const int kc = (chunk & 3) * 8;
      const bf16x8 va = *(const bf16x8*)&P[(size_t)(i0 + row) * 4096 + kt + kc];
      const bf16x8 vb = *(const bf16x8*)&Vt[(size_t)(n0 + row) * 4096 + kt + kc];
      *(bf16x8*)&lds_a[row * 40 + kc] = va;
      *(bf16x8*)&lds_b[row * 40 + kc] = vb;
    }
    __syncthreads();
    bf16x8 af[4], bfr[4];
#pragma unroll
    for (int f = 0; f < 4; ++f) {
      af[f]  = *(const bf16x8*)&lds_a[(wm + f * 16 + lq) * 40 + quad * 8];
      bfr[f] = *(const bf16x8*)&lds_b[(wn + f * 16 + lq) * 40 + quad * 8];
    }
#pragma unroll
    for (int fm = 0; fm < 4; ++fm)
#pragma unroll
      for (int fn = 0; fn < 4; ++fn)
        acc[fm][fn] = __builtin_amdgcn_mfma_f32_16x16x32_bf16(af[fm], bfr[fn], acc[fm][fn], 0, 0, 0);
  }
#pragma unroll
  for (int fm = 0; fm < 4; ++fm)
#pragma unroll
    for (int r = 0; r < 4; ++r) {
      const int gm = i0 + wm + fm * 16 + quad * 4 + r;
      const float sc = inv[gm];
#pragma unroll
      for (int fn = 0; fn < 4; ++fn) {
        const int gn = n0 + wn + fn * 16 + lq;
        W[(size_t)gm * DD + gn] = acc[fm][fn][r] * sc;
      }
    }
}

// ---------------- elementwise finish (FP32 out): copy / a-w / a*w -----------
__global__ __launch_bounds__(256) void finish(const float* __restrict__ Ain,
                                              const float* __restrict__ Bin,
                                              float* __restrict__ out) {
  const int side = blockIdx.x >> 11;
  const int blk = blockIdx.x & 2047;
  const size_t idx = ((size_t)blk * 256 + threadIdx.x) * 8;
  const size_t S = (size_t)LA * DD;  // 4M elements per slot
  const float* src = side ? Bin : Ain;
  float* ob = out + (size_t)side * 4 * S;
  const float4 a0 = *(const float4*)&src[idx];
  const float4 a1 = *(const float4*)&src[idx + 4];
  const float4 w0 = *(const float4*)&ob[S + idx];      // wave (final home)
  const float4 w1 = *(const float4*)&ob[S + idx + 4];
  float4 s0, s1, m0, m1;
  s0.x = a0.x - w0.x; s0.y = a0.y - w0.y; s0.z = a0.z - w0.z; s0.w = a0.w - w0.w;
  s1.x = a1.x - w1.x; s1.y = a1.y - w1.y; s1.z = a1.z - w1.z; s1.w = a1.w - w1.w;
  m0.x = a0.x * w0.x; m0.y = a0.y * w0.y; m0.z = a0.z * w0.z; m0.w = a0.w * w0.w;
  m1.x = a1.x * w1.x; m1.y = a1.y * w1.y; m1.z = a1.z * w1.z; m1.w = a1.w * w1.w;
  *(float4*)&ob[idx] = a0;            *(float4*)&ob[idx + 4] = a1;
  *(float4*)&ob[2 * S + idx] = s0;    *(float4*)&ob[2 * S + idx + 4] = s1;
  *(float4*)&ob[3 * S + idx] = m0;    *(float4*)&ob[3 * S + idx + 4] = m1;
}

extern "C" void kernel_launch(void* const* d_in, const int* in_sizes, int n_in,
                              void* d_out, int out_size, void* d_ws, size_t ws_size,
                              hipStream_t stream) {
  const float* A = (const float*)d_in[0];
  const float* B = (const float*)d_in[1];
  float* out = (float*)d_out;          // FP32 output: 8 slots of S floats
  const size_t S = (size_t)LA * DD;    // 4,194,304

  // d_ws UNUSED. Scratch choreography inside the 128 MiB fp32 out buffer:
  //   slot0 [0,S):   stats (1.1MB) + Bt (floats [1M,3M)) ; finish side0 copy LAST
  //   slot1 [S,2S):  wave_a final home
  //   slot2-3:       P (16M u16 = 2S floats) ; finish side0 sub/mul LAST
  //   slot4-7 (m_b): E [4096][4096] fp32 = 4S ; then At->slot4, wave_b->slot5,
  //                  finish side1 copy/sub/mul -> slots 4/6/7
  float* pmax = out;                       // 131072
  float* psum = pmax + 131072;             // 131072
  float* rmax = psum + 131072;             // 4096
  float* rinv = rmax + 4096;
  float* cmax = rinv + 4096;
  float* cinv = cmax + 4096;               // ends at 278528 floats (~1.06MB)
  u16*   Bt   = (u16*)(out + 1048576);     // [DD][LB] u16, 8MB
  u16*   P    = (u16*)(out + 2 * S);       // [4096][4096] u16, 32MB
  float* E    = out + 4 * S;               // [4096][4096] fp32, 64MB
  u16*   At   = (u16*)(out + 4 * S);       // [DD][LA] u16, 8MB (E consumed)
  float* wave_a = out + S;
  float* wave_b = out + 5 * S;

  // E (slots 4-7), fp32-accurate
  gemm_energy<<<dim3(LB / 128, LA / 128), 256, 0, stream>>>(A, B, E);
  // softmax stats (slot0)
  row_stats<<<dim3(LA), 256, 0, stream>>>(E, rmax, rinv);
  col_partial<<<dim3(LB / 256, 32), 256, 0, stream>>>(E, pmax, psum);
  col_combine<<<dim3(LB / 256), 256, 0, stream>>>(pmax, psum, cmax, cinv);

  // wave_a: Pa (slots 2-3), Bt (slot0 tail), gemm -> slot1
  tr_f32<<<dim3(DD / 32, LB / 32), 256, 0, stream>>>(B, Bt, LB, DD);
  make_pa<<<dim3(LA), 256, 0, stream>>>(E, rmax, P);
  gemm_pv<<<dim3(DD / 128, LA / 128), 256, 0, stream>>>(P, Bt, rinv, wave_a);

  // wave_b: Pb (slots 2-3, overwrites Pa), At (slot4, E consumed), gemm -> slot5
  make_pb<<<dim3(LB / 32, LA / 32), 256, 0, stream>>>(E, cmax, P);
  tr_f32<<<dim3(DD / 32, LA / 32), 256, 0, stream>>>(A, At, LA, DD);
  gemm_pv<<<dim3(DD / 128, LB / 128), 256, 0, stream>>>(P, At, cinv, wave_b);

  // fill copy/sub/mul for both sides (clobbers all scratch, already consumed)
  finish<<<dim3(4096), 256, 0, stream>>>(A, B, out);
}

// Round 10
// 501.881 us; speedup vs baseline: 1.1784x; 1.1784x over previous
//
#include <hip/hip_runtime.h>
#include <cstdint>
#include <cstddef>

#define LA 4096
#define LB 4096
#define DD 1024

typedef unsigned short u16;
typedef short bf16x8 __attribute__((ext_vector_type(8)));
typedef float f32x4 __attribute__((ext_vector_type(4)));

__device__ __forceinline__ u16 f2bf(float f) {
  unsigned u = __builtin_bit_cast(unsigned, f);
  u += 0x7fffu + ((u >> 16) & 1u);
  return (u16)(u >> 16);
}
__device__ __forceinline__ float bf2f(u16 h) {
  return __builtin_bit_cast(float, (unsigned)h << 16);
}
__device__ __forceinline__ bf16x8 pack8(float4 a, float4 b) {
  bf16x8 r;
  r[0] = (short)f2bf(a.x); r[1] = (short)f2bf(a.y);
  r[2] = (short)f2bf(a.z); r[3] = (short)f2bf(a.w);
  r[4] = (short)f2bf(b.x); r[5] = (short)f2bf(b.y);
  r[6] = (short)f2bf(b.z); r[7] = (short)f2bf(b.w);
  return r;
}
// async global->LDS, 16B/lane; lds base must be wave-uniform (HW adds lane*16)
__device__ __forceinline__ void async16(const void* g, void* l) {
  __builtin_amdgcn_global_load_lds(
      (const __attribute__((address_space(1))) unsigned int*)g,
      (__attribute__((address_space(3))) unsigned int*)l, 16, 0, 0);
}

// ---- prepass: split fp32 X -> Xhi + Xlo (bf16 residual pair) ---------------
__global__ __launch_bounds__(256) void split_ab(const float* __restrict__ A,
                                                const float* __restrict__ B,
                                                u16* __restrict__ Ahi, u16* __restrict__ Alo,
                                                u16* __restrict__ Bhi, u16* __restrict__ Blo) {
  const int side = blockIdx.x >> 11;
  const size_t idx = ((size_t)(blockIdx.x & 2047) * 256 + threadIdx.x) * 8;
  const float* src = side ? B : A;
  u16* dh = side ? Bhi : Ahi;
  u16* dl = side ? Blo : Alo;
  const float4 a = *(const float4*)&src[idx];
  const float4 b = *(const float4*)&src[idx + 4];
  float v[8] = {a.x, a.y, a.z, a.w, b.x, b.y, b.z, b.w};
  bf16x8 hi, lo;
#pragma unroll
  for (int i = 0; i < 8; ++i) {
    const u16 h = f2bf(v[i]);
    hi[i] = (short)h;
    lo[i] = (short)f2bf(v[i] - bf2f(h));
  }
  *(bf16x8*)&dh[idx] = hi;
  *(bf16x8*)&dl[idx] = lo;
}

// ------- tiled transpose fp32 -> bf16: out[c][r] = bf16(in[r][c]) -----------
__global__ __launch_bounds__(256) void tr_f32(const float* __restrict__ in,
                                              u16* __restrict__ out,
                                              int R, int C) {
  __shared__ u16 t[32][33];
  const int c0 = blockIdx.x * 32, r0 = blockIdx.y * 32;
  const int tid = threadIdx.x;
  const int lr = tid >> 3, lc = (tid & 7) * 4;
  const float4 v = *(const float4*)&in[(size_t)(r0 + lr) * C + c0 + lc];
  t[lr][lc + 0] = f2bf(v.x); t[lr][lc + 1] = f2bf(v.y);
  t[lr][lc + 2] = f2bf(v.z); t[lr][lc + 3] = f2bf(v.w);
  __syncthreads();
  ushort4 w;
  w.x = t[lc + 0][lr]; w.y = t[lc + 1][lr]; w.z = t[lc + 2][lr]; w.w = t[lc + 3][lr];
  *(ushort4*)&out[(size_t)(c0 + lr) * R + r0 + lc] = w;
}

// ------- energy = A @ B^T, split-bf16 3-term, ASYNC staging (m97-style) -----
__global__ __launch_bounds__(256) void gemm_energy(const u16* __restrict__ Ahi,
                                                   const u16* __restrict__ Alo,
                                                   const u16* __restrict__ Bhi,
                                                   const u16* __restrict__ Blo,
                                                   float* __restrict__ E) {
  __shared__ u16 lah[128 * 32], lal[128 * 32], lbh[128 * 32], lbl[128 * 32];
  const int j0 = blockIdx.x * 128;
  const int i0 = blockIdx.y * 128;
  const int tid = threadIdx.x;
  const int lane = tid & 63, quad = lane >> 4, lq = lane & 15;
  const int wave = tid >> 6;
  const int wm = (wave & 1) * 64, wn = (wave >> 1) * 64;
  f32x4 acc[4][4] = {};
  for (int kt = 0; kt < DD; kt += 32) {
    if (kt) __syncthreads();
#pragma unroll
    for (int r = 0; r < 2; ++r) {
      const int chunk = wave * 128 + r * 64 + lane;
      const int row = chunk >> 2;
      const int kc = (chunk & 3) * 8;
      const int lofs = (wave * 128 + r * 64) * 16;
      const size_t ga = (size_t)(i0 + row) * DD + kt + kc;
      const size_t gb = (size_t)(j0 + row) * DD + kt + kc;
      async16(Ahi + ga, (char*)lah + lofs);
      async16(Alo + ga, (char*)lal + lofs);
      async16(Bhi + gb, (char*)lbh + lofs);
      async16(Blo + gb, (char*)lbl + lofs);
    }
    __syncthreads();
    bf16x8 fah[4], fal[4], fbh[4], fbl[4];
#pragma unroll
    for (int f = 0; f < 4; ++f) {
      fah[f] = *(const bf16x8*)&lah[(wm + f * 16 + lq) * 32 + quad * 8];
      fal[f] = *(const bf16x8*)&lal[(wm + f * 16 + lq) * 32 + quad * 8];
      fbh[f] = *(const bf16x8*)&lbh[(wn + f * 16 + lq) * 32 + quad * 8];
      fbl[f] = *(const bf16x8*)&lbl[(wn + f * 16 + lq) * 32 + quad * 8];
    }
#pragma unroll
    for (int fm = 0; fm < 4; ++fm)
#pragma unroll
      for (int fn = 0; fn < 4; ++fn) {
        acc[fm][fn] = __builtin_amdgcn_mfma_f32_16x16x32_bf16(fal[fm], fbh[fn], acc[fm][fn], 0, 0, 0);
        acc[fm][fn] = __builtin_amdgcn_mfma_f32_16x16x32_bf16(fah[fm], fbl[fn], acc[fm][fn], 0, 0, 0);
        acc[fm][fn] = __builtin_amdgcn_mfma_f32_16x16x32_bf16(fah[fm], fbh[fn], acc[fm][fn], 0, 0, 0);
      }
  }
#pragma unroll
  for (int fm = 0; fm < 4; ++fm)
#pragma unroll
    for (int fn = 0; fn < 4; ++fn)
#pragma unroll
      for (int r = 0; r < 4; ++r) {
        const int gi = i0 + wm + fm * 16 + quad * 4 + r;
        const int gj = j0 + wn + fn * 16 + lq;
        E[(size_t)gi * LB + gj] = acc[fm][fn][r];
      }
}

// ---------------- row softmax stats -----------------------------------------
__global__ __launch_bounds__(256) void row_stats(const float* __restrict__ E,
                                                 float* __restrict__ rmax,
                                                 float* __restrict__ rinv) {
  __shared__ float red[8];
  const int row = blockIdx.x, tid = threadIdx.x;
  const float* e = E + (size_t)row * LB;
  float4 v[4];
#pragma unroll
  for (int c = 0; c < 4; ++c) v[c] = *(const float4*)&e[(c * 256 + tid) * 4];
  float m = -__builtin_inff();
#pragma unroll
  for (int c = 0; c < 4; ++c)
    m = fmaxf(m, fmaxf(fmaxf(v[c].x, v[c].y), fmaxf(v[c].z, v[c].w)));
#pragma unroll
  for (int o = 32; o > 0; o >>= 1) m = fmaxf(m, __shfl_down(m, o));
  if ((tid & 63) == 0) red[tid >> 6] = m;
  __syncthreads();
  m = fmaxf(fmaxf(red[0], red[1]), fmaxf(red[2], red[3]));
  float s = 0.f;
#pragma unroll
  for (int c = 0; c < 4; ++c)
    s += __expf(v[c].x - m) + __expf(v[c].y - m) + __expf(v[c].z - m) + __expf(v[c].w - m);
#pragma unroll
  for (int o = 32; o > 0; o >>= 1) s += __shfl_down(s, o);
  if ((tid & 63) == 0) red[4 + (tid >> 6)] = s;
  __syncthreads();
  if (tid == 0) {
    rmax[row] = m;
    rinv[row] = 1.f / (red[4] + red[5] + red[6] + red[7]);
  }
}

// ---------------- column softmax stats --------------------------------------
__global__ __launch_bounds__(256) void col_partial(const float* __restrict__ E,
                                                   float* __restrict__ pmax,
                                                   float* __restrict__ psum) {
  const int c = blockIdx.x * 256 + threadIdx.x;
  const int rg = blockIdx.y;
  const float* e = E + (size_t)rg * 128 * LB + c;
  float m = -__builtin_inff(), s = 0.f;
#pragma unroll 4
  for (int r = 0; r < 128; ++r) {
    const float x = e[(size_t)r * LB];
    const float nm = fmaxf(m, x);
    s = s * __expf(m - nm) + __expf(x - nm);
    m = nm;
  }
  pmax[rg * LB + c] = m;
  psum[rg * LB + c] = s;
}

__global__ __launch_bounds__(256) void col_combine(const float* __restrict__ pmax,
                                                   const float* __restrict__ psum,
                                                   float* __restrict__ cmax,
                                                   float* __restrict__ cinv) {
  const int c = blockIdx.x * 256 + threadIdx.x;
  float m = -__builtin_inff(), s = 0.f;
#pragma unroll 4
  for (int g = 0; g < 32; ++g) {
    const float pm = pmax[g * LB + c], ps = psum[g * LB + c];
    const float nm = fmaxf(m, pm);
    s = s * __expf(m - nm) + ps * __expf(pm - nm);
    m = nm;
  }
  cmax[c] = m;
  cinv[c] = 1.f / s;
}

// ---- Pa[i][j] = bf16(exp(E[i][j] - rmax[i])) -------------------------------
__global__ __launch_bounds__(256) void make_pa(const float* __restrict__ E,
                                               const float* __restrict__ rmax,
                                               u16* __restrict__ P) {
  const int i = blockIdx.x;
  const int c = threadIdx.x * 16;
  const float* e = E + (size_t)i * LB + c;
  const float rm = rmax[i];
  const float4 x0 = *(const float4*)(e);
  const float4 x1 = *(const float4*)(e + 4);
  const float4 x2 = *(const float4*)(e + 8);
  const float4 x3 = *(const float4*)(e + 12);
  float4 y0, y1, y2, y3;
  y0.x = __expf(x0.x - rm); y0.y = __expf(x0.y - rm); y0.z = __expf(x0.z - rm); y0.w = __expf(x0.w - rm);
  y1.x = __expf(x1.x - rm); y1.y = __expf(x1.y - rm); y1.z = __expf(x1.z - rm); y1.w = __expf(x1.w - rm);
  y2.x = __expf(x2.x - rm); y2.y = __expf(x2.y - rm); y2.z = __expf(x2.z - rm); y2.w = __expf(x2.w - rm);
  y3.x = __expf(x3.x - rm); y3.y = __expf(x3.y - rm); y3.z = __expf(x3.z - rm); y3.w = __expf(x3.w - rm);
  *(bf16x8*)&P[(size_t)i * LB + c] = pack8(y0, y1);
  *(bf16x8*)&P[(size_t)i * LB + c + 8] = pack8(y2, y3);
}

// ---- Pb[j][i] = bf16(exp(E[i][j] - cmax[j])), transposing ------------------
__global__ __launch_bounds__(256) void make_pb(const float* __restrict__ E,
                                               const float* __restrict__ cmax,
                                               u16* __restrict__ P) {
  __shared__ u16 t[32][33];
  const int j0 = blockIdx.x * 32;
  const int i0 = blockIdx.y * 32;
  const int tid = threadIdx.x;
  const int lr = tid >> 3, lc = (tid & 7) * 4;
  const float4 v = *(const float4*)&E[(size_t)(i0 + lr) * LB + j0 + lc];
  const float4 cm = *(const float4*)&cmax[j0 + lc];
  t[lr][lc + 0] = f2bf(__expf(v.x - cm.x));
  t[lr][lc + 1] = f2bf(__expf(v.y - cm.y));
  t[lr][lc + 2] = f2bf(__expf(v.z - cm.z));
  t[lr][lc + 3] = f2bf(__expf(v.w - cm.w));
  __syncthreads();
  ushort4 w;
  w.x = t[lc + 0][lr]; w.y = t[lc + 1][lr]; w.z = t[lc + 2][lr]; w.w = t[lc + 3][lr];
  *(ushort4*)&P[(size_t)(j0 + lr) * LA + i0 + lc] = w;
}

// ---- W[i][d] = inv[i] * sum_j P[i][j] Vt[d][j], ASYNC staging --------------
__global__ __launch_bounds__(256) void gemm_pv(const u16* __restrict__ P,
                                               const u16* __restrict__ Vt,
                                               const float* __restrict__ inv,
                                               float* __restrict__ W) {
  __shared__ u16 lds_a[128 * 32];
  __shared__ u16 lds_b[128 * 32];
  const int n0 = blockIdx.x * 128;
  const int i0 = blockIdx.y * 128;
  const int tid = threadIdx.x;
  const int lane = tid & 63, quad = lane >> 4, lq = lane & 15;
  const int wave = tid >> 6;
  const int wm = (wave & 1) * 64, wn = (wave >> 1) * 64;
  f32x4 acc[4][4] = {};
  for (int kt = 0; kt < 4096; kt += 32) {
    if (kt) __syncthreads();
#pragma unroll
    for (int r = 0; r < 2; ++r) {
      const int chunk = wave * 128 + r * 64 + lane;
      const int row = chunk >> 2;
      const int kc = (chunk & 3) * 8;
      const int lofs = (wave * 128 + r * 64) * 16;
      async16(P + (size_t)(i0 + row) * 4096 + kt + kc, (char*)lds_a + lofs);
      async16(Vt + (size_t)(n0 + row) * 4096 + kt + kc, (char*)lds_b + lofs);
    }
    __syncthreads();
    bf16x8 af[4], bfr[4];
#pragma unroll
    for (int f = 0; f < 4; ++f) {
      af[f]  = *(const bf16x8*)&lds_a[(wm + f * 16 + lq) * 32 + quad * 8];
      bfr[f] = *(const bf16x8*)&lds_b[(wn + f * 16 + lq) * 32 + quad * 8];
    }
#pragma unroll
    for (int fm = 0; fm < 4; ++fm)
#pragma unroll
      for (int fn = 0; fn < 4; ++fn)
        acc[fm][fn] = __builtin_amdgcn_mfma_f32_16x16x32_bf16(af[fm], bfr[fn], acc[fm][fn], 0, 0, 0);
  }
#pragma unroll
  for (int fm = 0; fm < 4; ++fm)
#pragma unroll
    for (int r = 0; r < 4; ++r) {
      const int gm = i0 + wm + fm * 16 + quad * 4 + r;
      const float sc = inv[gm];
#pragma unroll
      for (int fn = 0; fn < 4; ++fn) {
        const int gn = n0 + wn + fn * 16 + lq;
        W[(size_t)gm * DD + gn] = acc[fm][fn][r] * sc;
      }
    }
}

// ---------------- elementwise finish (FP32 out): copy / a-w / a*w -----------
__global__ __launch_bounds__(256) void finish(const float* __restrict__ Ain,
                                              const float* __restrict__ Bin,
                                              float* __restrict__ out) {
  const int side = blockIdx.x >> 11;
  const int blk = blockIdx.x & 2047;
  const size_t idx = ((size_t)blk * 256 + threadIdx.x) * 8;
  const size_t S = (size_t)LA * DD;
  const float* src = side ? Bin : Ain;
  float* ob = out + (size_t)side * 4 * S;
  const float4 a0 = *(const float4*)&src[idx];
  const float4 a1 = *(const float4*)&src[idx + 4];
  const float4 w0 = *(const float4*)&ob[S + idx];
  const float4 w1 = *(const float4*)&ob[S + idx + 4];
  float4 s0, s1, m0, m1;
  s0.x = a0.x - w0.x; s0.y = a0.y - w0.y; s0.z = a0.z - w0.z; s0.w = a0.w - w0.w;
  s1.x = a1.x - w1.x; s1.y = a1.y - w1.y; s1.z = a1.z - w1.z; s1.w = a1.w - w1.w;
  m0.x = a0.x * w0.x; m0.y = a0.y * w0.y; m0.z = a0.z * w0.z; m0.w = a0.w * w0.w;
  m1.x = a1.x * w1.x; m1.y = a1.y * w1.y; m1.z = a1.z * w1.z; m1.w = a1.w * w1.w;
  *(float4*)&ob[idx] = a0;            *(float4*)&ob[idx + 4] = a1;
  *(float4*)&ob[2 * S + idx] = s0;    *(float4*)&ob[2 * S + idx + 4] = s1;
  *(float4*)&ob[3 * S + idx] = m0;    *(float4*)&ob[3 * S + idx + 4] = m1;
}

extern "C" void kernel_launch(void* const* d_in, const int* in_sizes, int n_in,
                              void* d_out, int out_size, void* d_ws, size_t ws_size,
                              hipStream_t stream) {
  const float* A = (const float*)d_in[0];
  const float* B = (const float*)d_in[1];
  float* out = (float*)d_out;          // FP32 output: 8 slots of S floats
  const size_t S = (size_t)LA * DD;    // 4,194,304

  // d_ws UNUSED. Scratch choreography inside the 128 MiB fp32 out buffer:
  //   slot0: stats (1.1MB) + Bt (u16 at float-ofs 1M) ; finish side0 copy LAST
  //   slot1: wave_a final home
  //   slots2-3: Ahi/Alo/Bhi/Blo (4x8MB) -> then P (32MB) ; finish sub/mul LAST
  //   slots4-7: E (64MB) -> then At (slot4), wave_b (slot5), finish side1
  float* pmax = out;                       // 131072
  float* psum = pmax + 131072;             // 131072
  float* rmax = psum + 131072;             // 4096
  float* rinv = rmax + 4096;
  float* cmax = rinv + 4096;
  float* cinv = cmax + 4096;
  u16*   Bt   = (u16*)(out + 1048576);     // [DD][LB] u16, 8MB
  u16*   Ahi  = (u16*)(out + 2 * S);       // 8MB each
  u16*   Alo  = Ahi + S;
  u16*   Bhi  = Alo + S;
  u16*   Blo  = Bhi + S;
  u16*   P    = (u16*)(out + 2 * S);       // [4096][4096] u16 (after hi/lo dead)
  float* E    = out + 4 * S;               // [4096][4096] fp32, 64MB
  u16*   At   = (u16*)(out + 4 * S);       // [DD][LA] u16 (after E consumed)
  float* wave_a = out + S;
  float* wave_b = out + 5 * S;

  split_ab<<<dim3(4096), 256, 0, stream>>>(A, B, Ahi, Alo, Bhi, Blo);
  gemm_energy<<<dim3(LB / 128, LA / 128), 256, 0, stream>>>(Ahi, Alo, Bhi, Blo, E);
  row_stats<<<dim3(LA), 256, 0, stream>>>(E, rmax, rinv);
  col_partial<<<dim3(LB / 256, 32), 256, 0, stream>>>(E, pmax, psum);
  col_combine<<<dim3(LB / 256), 256, 0, stream>>>(pmax, psum, cmax, cinv);

  // wave_a
  tr_f32<<<dim3(DD / 32, LB / 32), 256, 0, stream>>>(B, Bt, LB, DD);
  make_pa<<<dim3(LA), 256, 0, stream>>>(E, rmax, P);
  gemm_pv<<<dim3(DD / 128, LA / 128), 256, 0, stream>>>(P, Bt, rinv, wave_a);

  // wave_b
  make_pb<<<dim3(LB / 32, LA / 32), 256, 0, stream>>>(E, cmax, P);
  tr_f32<<<dim3(DD / 32, LA / 32), 256, 0, stream>>>(A, At, LA, DD);
  gemm_pv<<<dim3(DD / 128, LB / 128), 256, 0, stream>>>(P, At, cinv, wave_b);

  finish<<<dim3(4096), 256, 0, stream>>>(A, B, out);
}